// Round 1
// baseline (2741.380 us; speedup 1.0000x reference)
//
#include <hip/hip_runtime.h>

// LightGCN propagation: out = mean(x0, x1, x2, x3), x_{k+1} = SpMM(COO, x_k)
// N_NODES=300000, DIM=64, NNZ=4,000,000

#define N_USERS  100000
#define N_ITEMS  200000
#define N_NODES_ 300000
#define DIM      64
#define NNZ_     4000000

// ---------------- init: A = concat(user, item); out = A ----------------
__global__ void init_kernel(const float4* __restrict__ u, const float4* __restrict__ it,
                            float4* __restrict__ A, float4* __restrict__ out) {
    const int n_u4 = N_USERS * DIM / 4;
    const int n_t4 = N_NODES_ * DIM / 4;
    int i = blockIdx.x * blockDim.x + threadIdx.x;
    if (i >= n_t4) return;
    float4 v = (i < n_u4) ? u[i] : it[i - n_u4];
    A[i] = v;
    out[i] = v;
}

// ---------------- spmm: y[row] += val * x[col], one wave per edge ----------------
__global__ void spmm_kernel(const int* __restrict__ rows, const int* __restrict__ cols,
                            const float* __restrict__ vals, const float* __restrict__ x,
                            float* __restrict__ y) {
    const int wavesPerBlock = blockDim.x >> 6;
    const int lane = threadIdx.x & 63;
    int wave = blockIdx.x * wavesPerBlock + (threadIdx.x >> 6);
    const int stride = gridDim.x * wavesPerBlock;
    for (int e = wave; e < NNZ_; e += stride) {
        int   r = rows[e];
        int   c = cols[e];
        float v = vals[e];
        float xv = x[(size_t)c * DIM + lane];
        unsafeAtomicAdd(&y[(size_t)r * DIM + lane], v * xv);
    }
}

// ---------------- acc_zero: out += src; zbuf = 0 ----------------
__global__ void acc_zero_kernel(float4* __restrict__ out, const float4* __restrict__ src,
                                float4* __restrict__ zbuf) {
    const int n_t4 = N_NODES_ * DIM / 4;
    int i = blockIdx.x * blockDim.x + threadIdx.x;
    if (i >= n_t4) return;
    float4 o = out[i];
    float4 s = src[i];
    o.x += s.x; o.y += s.y; o.z += s.z; o.w += s.w;
    out[i] = o;
    zbuf[i] = make_float4(0.f, 0.f, 0.f, 0.f);
}

// ---------------- final: out = (out + src) * 0.25 ----------------
__global__ void final_kernel(float4* __restrict__ out, const float4* __restrict__ src) {
    const int n_t4 = N_NODES_ * DIM / 4;
    int i = blockIdx.x * blockDim.x + threadIdx.x;
    if (i >= n_t4) return;
    float4 o = out[i];
    float4 s = src[i];
    o.x = (o.x + s.x) * 0.25f;
    o.y = (o.y + s.y) * 0.25f;
    o.z = (o.z + s.z) * 0.25f;
    o.w = (o.w + s.w) * 0.25f;
    out[i] = o;
}

extern "C" void kernel_launch(void* const* d_in, const int* in_sizes, int n_in,
                              void* d_out, int out_size, void* d_ws, size_t ws_size,
                              hipStream_t stream) {
    const float* user_emb = (const float*)d_in[0];
    const float* item_emb = (const float*)d_in[1];
    const int*   rows     = (const int*)d_in[2];
    const int*   cols     = (const int*)d_in[3];
    const float* vals     = (const float*)d_in[4];
    float* out = (float*)d_out;

    const size_t nElems = (size_t)N_NODES_ * DIM;      // 19.2M floats
    float* A = (float*)d_ws;
    float* B = A + nElems;

    const int n_t4 = (int)(nElems / 4);                // 4.8M float4s
    const int ew_block = 256;
    const int ew_grid  = (n_t4 + ew_block - 1) / ew_block;

    const int sp_block = 256;
    const int sp_grid  = 32768;                        // grid-stride, 131072 waves

    // B must be zero before first spmm
    hipMemsetAsync(B, 0, nElems * sizeof(float), stream);

    // x0 = concat; out = x0
    init_kernel<<<ew_grid, ew_block, 0, stream>>>((const float4*)user_emb,
                                                  (const float4*)item_emb,
                                                  (float4*)A, (float4*)out);
    // layer 1: A -> B
    spmm_kernel<<<sp_grid, sp_block, 0, stream>>>(rows, cols, vals, A, B);
    // out += x1; zero A for layer 2 output
    acc_zero_kernel<<<ew_grid, ew_block, 0, stream>>>((float4*)out, (const float4*)B, (float4*)A);
    // layer 2: B -> A
    spmm_kernel<<<sp_grid, sp_block, 0, stream>>>(rows, cols, vals, B, A);
    // out += x2; zero B for layer 3 output
    acc_zero_kernel<<<ew_grid, ew_block, 0, stream>>>((float4*)out, (const float4*)A, (float4*)B);
    // layer 3: A -> B
    spmm_kernel<<<sp_grid, sp_block, 0, stream>>>(rows, cols, vals, A, B);
    // out = (out + x3) / 4
    final_kernel<<<ew_grid, ew_block, 0, stream>>>((float4*)out, (const float4*)B);
}

// Round 2
// 1349.595 us; speedup vs baseline: 2.0313x; 2.0313x over previous
//
#include <hip/hip_runtime.h>

// LightGCN propagation: out = mean(x0..x3), x_{k+1} = SpMM(COO, x_k)
// Strategy: counting-sort edges by row into CSR once, then 3 atomic-free
// SpMM passes (one wave per row, lane = embedding dim).

#define N_USERS  100000
#define N_ITEMS  200000
#define N_NODES_ 300000
#define DIM      64
#define NNZ_     4000000
#define SCAN_CHUNK 2048                         // 256 threads x 8 elems
#define NBLK ((N_NODES_ + SCAN_CHUNK - 1) / SCAN_CHUNK)   // 147

// ---------------- init: A = concat(user, item); out = A ----------------
__global__ void init_kernel(const float4* __restrict__ u, const float4* __restrict__ it,
                            float4* __restrict__ A, float4* __restrict__ out) {
    const int n_u4 = N_USERS * DIM / 4;
    const int n_t4 = N_NODES_ * DIM / 4;
    int i = blockIdx.x * blockDim.x + threadIdx.x;
    if (i >= n_t4) return;
    float4 v = (i < n_u4) ? u[i] : it[i - n_u4];
    A[i] = v;
    out[i] = v;
}

// ---------------- histogram of row ids ----------------
__global__ void hist_kernel(const int* __restrict__ rows, int* __restrict__ counts) {
    int e = blockIdx.x * blockDim.x + threadIdx.x;
    if (e < NNZ_) atomicAdd(&counts[rows[e]], 1);
}

// ---------------- scan phase A: per-block exclusive scan + block sums ----------------
__global__ void scan_a(const int* __restrict__ counts, int* __restrict__ row_start,
                       int* __restrict__ blockSums) {
    __shared__ int lds[256];
    int tid = threadIdx.x;
    int base = blockIdx.x * SCAN_CHUNK + tid * 8;
    int v[8]; int sum = 0;
    #pragma unroll
    for (int k = 0; k < 8; ++k) {
        int idx = base + k;
        v[k] = (idx < N_NODES_) ? counts[idx] : 0;
        sum += v[k];
    }
    lds[tid] = sum;
    __syncthreads();
    for (int off = 1; off < 256; off <<= 1) {
        int t = (tid >= off) ? lds[tid - off] : 0;
        __syncthreads();
        lds[tid] += t;
        __syncthreads();
    }
    int excl = (tid == 0) ? 0 : lds[tid - 1];
    #pragma unroll
    for (int k = 0; k < 8; ++k) {
        int idx = base + k;
        if (idx < N_NODES_) row_start[idx] = excl;
        excl += v[k];
    }
    if (tid == 255) blockSums[blockIdx.x] = lds[255];
}

// ---------------- scan phase B: scan the 147 block sums (one block) ----------------
__global__ void scan_b(int* __restrict__ blockSums) {
    __shared__ int lds[256];
    int tid = threadIdx.x;
    int v = (tid < NBLK) ? blockSums[tid] : 0;
    lds[tid] = v;
    __syncthreads();
    for (int off = 1; off < 256; off <<= 1) {
        int t = (tid >= off) ? lds[tid - off] : 0;
        __syncthreads();
        lds[tid] += t;
        __syncthreads();
    }
    int excl = (tid == 0) ? 0 : lds[tid - 1];
    if (tid < NBLK) blockSums[tid] = excl;
}

// ---------------- scan phase C: add block offsets; init cursor; sentinel ----------------
__global__ void scan_c(int* __restrict__ row_start, int* __restrict__ cursor,
                       const int* __restrict__ blockSums) {
    int idx = blockIdx.x * blockDim.x + threadIdx.x;
    if (idx < N_NODES_) {
        int r = row_start[idx] + blockSums[idx >> 11];   // 2048 = 1<<11
        row_start[idx] = r;
        cursor[idx] = r;
    } else if (idx == N_NODES_) {
        row_start[idx] = NNZ_;
    }
}

// ---------------- scatter edges into CSR order ----------------
__global__ void scatter_kernel(const int* __restrict__ rows, const int* __restrict__ cols,
                               const float* __restrict__ vals, int* __restrict__ cursor,
                               int2* __restrict__ sedge) {
    int e = blockIdx.x * blockDim.x + threadIdx.x;
    if (e >= NNZ_) return;
    int r = rows[e];
    int pos = atomicAdd(&cursor[r], 1);
    sedge[pos] = make_int2(cols[e], __float_as_int(vals[e]));
}

// ---------------- CSR SpMM: one wave per row; fused mean accumulate ----------------
// FINAL=0: y[r] = acc; out[r] += acc.   FINAL=1: out[r] = (out[r]+acc)*0.25
template <int FINAL>
__global__ __launch_bounds__(256) void spmm_csr(const int* __restrict__ row_start,
                                                const int2* __restrict__ sedge,
                                                const float* __restrict__ x,
                                                float* __restrict__ y,
                                                float* __restrict__ out) {
    int w = blockIdx.x * 4 + (threadIdx.x >> 6);
    if (w >= N_NODES_) return;
    int lane = threadIdx.x & 63;
    int s = row_start[w];
    int e = row_start[w + 1];
    float acc = 0.f;
    for (int base = s; base < e; base += 64) {
        int n = e - base;
        if (n > 64) n = 64;
        int2 ed = (lane < n) ? sedge[base + lane] : make_int2(0, 0);
        for (int j = 0; j < n; ++j) {
            int   cj = __shfl(ed.x, j);
            float vj = __int_as_float(__shfl(ed.y, j));
            acc += vj * x[(size_t)cj * DIM + lane];
        }
    }
    size_t o = (size_t)w * DIM + lane;
    if (FINAL) {
        out[o] = (out[o] + acc) * 0.25f;
    } else {
        y[o] = acc;
        out[o] += acc;
    }
}

extern "C" void kernel_launch(void* const* d_in, const int* in_sizes, int n_in,
                              void* d_out, int out_size, void* d_ws, size_t ws_size,
                              hipStream_t stream) {
    const float* user_emb = (const float*)d_in[0];
    const float* item_emb = (const float*)d_in[1];
    const int*   rows     = (const int*)d_in[2];
    const int*   cols     = (const int*)d_in[3];
    const float* vals     = (const float*)d_in[4];
    float* out = (float*)d_out;

    const size_t nE = (size_t)N_NODES_ * DIM;          // 19.2M floats
    float* A         = (float*)d_ws;                   // 76.8 MB
    float* B         = A + nE;                         // 76.8 MB
    int*   row_start = (int*)(B + nE);                 // 300002 ints (padded even)
    int*   cursor    = row_start + (N_NODES_ + 2);     // 300000 ints (doubles as counts)
    int*   blockSums = cursor + N_NODES_;              // 256 ints
    int2*  sedge     = (int2*)(blockSums + 256);       // 32 MB, 8B-aligned

    int* counts = cursor;   // alias: hist->counts, scan_a consumes, scan_c overwrites w/ cursor

    const int n_t4 = (int)(nE / 4);
    const int ew_grid = (n_t4 + 255) / 256;
    const int edge_grid = (NNZ_ + 255) / 256;          // 15625
    const int spmm_grid = (N_NODES_ + 3) / 4;          // 75000 (4 waves/block)

    // ---- build CSR (amortized over 3 layers) ----
    hipMemsetAsync(counts, 0, N_NODES_ * sizeof(int), stream);
    hist_kernel<<<edge_grid, 256, 0, stream>>>(rows, counts);
    scan_a<<<NBLK, 256, 0, stream>>>(counts, row_start, blockSums);
    scan_b<<<1, 256, 0, stream>>>(blockSums);
    scan_c<<<(N_NODES_ + 1 + 255) / 256, 256, 0, stream>>>(row_start, cursor, blockSums);
    scatter_kernel<<<edge_grid, 256, 0, stream>>>(rows, cols, vals, cursor, sedge);

    // ---- x0 = concat; out = x0 ----
    init_kernel<<<ew_grid, 256, 0, stream>>>((const float4*)user_emb,
                                             (const float4*)item_emb,
                                             (float4*)A, (float4*)out);
    // ---- layer 1: A -> B, out += x1 ----
    spmm_csr<0><<<spmm_grid, 256, 0, stream>>>(row_start, sedge, A, B, out);
    // ---- layer 2: B -> A, out += x2 ----
    spmm_csr<0><<<spmm_grid, 256, 0, stream>>>(row_start, sedge, B, A, out);
    // ---- layer 3: A -> out, out = (out + x3)/4 ----
    spmm_csr<1><<<spmm_grid, 256, 0, stream>>>(row_start, sedge, A, nullptr, out);
}

// Round 3
// 1148.289 us; speedup vs baseline: 2.3874x; 1.1753x over previous
//
#include <hip/hip_runtime.h>

// LightGCN propagation: out = mean(x0..x3), x_{k+1} = SpMM(COO, x_k)
// CSR counting-sort once, then 3 atomic-free SpMM passes.
// SpMM v2: wave = 1 row, 4 edge-groups x 16 lanes x float4 -> dwordx4 gathers,
// unroll 2, dual accumulators, shfl_xor group reduce.

#define N_USERS  100000
#define N_ITEMS  200000
#define N_NODES_ 300000
#define DIM      64
#define NNZ_     4000000
#define SCAN_CHUNK 2048                         // 256 threads x 8 elems
#define NBLK ((N_NODES_ + SCAN_CHUNK - 1) / SCAN_CHUNK)   // 147

// ---------------- init: A = concat(user, item); out = A ----------------
__global__ void init_kernel(const float4* __restrict__ u, const float4* __restrict__ it,
                            float4* __restrict__ A, float4* __restrict__ out) {
    const int n_u4 = N_USERS * DIM / 4;
    const int n_t4 = N_NODES_ * DIM / 4;
    int i = blockIdx.x * blockDim.x + threadIdx.x;
    if (i >= n_t4) return;
    float4 v = (i < n_u4) ? u[i] : it[i - n_u4];
    A[i] = v;
    out[i] = v;
}

// ---------------- histogram of row ids ----------------
__global__ void hist_kernel(const int* __restrict__ rows, int* __restrict__ counts) {
    int e = blockIdx.x * blockDim.x + threadIdx.x;
    if (e < NNZ_) atomicAdd(&counts[rows[e]], 1);
}

// ---------------- scan phase A ----------------
__global__ void scan_a(const int* __restrict__ counts, int* __restrict__ row_start,
                       int* __restrict__ blockSums) {
    __shared__ int lds[256];
    int tid = threadIdx.x;
    int base = blockIdx.x * SCAN_CHUNK + tid * 8;
    int v[8]; int sum = 0;
    #pragma unroll
    for (int k = 0; k < 8; ++k) {
        int idx = base + k;
        v[k] = (idx < N_NODES_) ? counts[idx] : 0;
        sum += v[k];
    }
    lds[tid] = sum;
    __syncthreads();
    for (int off = 1; off < 256; off <<= 1) {
        int t = (tid >= off) ? lds[tid - off] : 0;
        __syncthreads();
        lds[tid] += t;
        __syncthreads();
    }
    int excl = (tid == 0) ? 0 : lds[tid - 1];
    #pragma unroll
    for (int k = 0; k < 8; ++k) {
        int idx = base + k;
        if (idx < N_NODES_) row_start[idx] = excl;
        excl += v[k];
    }
    if (tid == 255) blockSums[blockIdx.x] = lds[255];
}

// ---------------- scan phase B ----------------
__global__ void scan_b(int* __restrict__ blockSums) {
    __shared__ int lds[256];
    int tid = threadIdx.x;
    int v = (tid < NBLK) ? blockSums[tid] : 0;
    lds[tid] = v;
    __syncthreads();
    for (int off = 1; off < 256; off <<= 1) {
        int t = (tid >= off) ? lds[tid - off] : 0;
        __syncthreads();
        lds[tid] += t;
        __syncthreads();
    }
    int excl = (tid == 0) ? 0 : lds[tid - 1];
    if (tid < NBLK) blockSums[tid] = excl;
}

// ---------------- scan phase C ----------------
__global__ void scan_c(int* __restrict__ row_start, int* __restrict__ cursor,
                       const int* __restrict__ blockSums) {
    int idx = blockIdx.x * blockDim.x + threadIdx.x;
    if (idx < N_NODES_) {
        int r = row_start[idx] + blockSums[idx >> 11];
        row_start[idx] = r;
        cursor[idx] = r;
    } else if (idx == N_NODES_) {
        row_start[idx] = NNZ_;
    }
}

// ---------------- scatter edges into CSR order (nontemporal stores) ----------------
__global__ void scatter_kernel(const int* __restrict__ rows, const int* __restrict__ cols,
                               const float* __restrict__ vals, int* __restrict__ cursor,
                               long long* __restrict__ sedge) {
    int e = blockIdx.x * blockDim.x + threadIdx.x;
    if (e >= NNZ_) return;
    int r = rows[e];
    int pos = atomicAdd(&cursor[r], 1);
    long long p = ((long long)(unsigned)__float_as_int(vals[e]) << 32) | (unsigned)cols[e];
    __builtin_nontemporal_store(p, &sedge[pos]);
}

// ---------------- CSR SpMM v2 ----------------
// wave = one row. lane = g*16 + d: g = edge subgroup (0..3), d = float4 dim chunk.
// FINAL=0: y[r] = acc; out[r] += acc.   FINAL=1: out[r] = (out[r]+acc)*0.25
template <int FINAL>
__global__ __launch_bounds__(256) void spmm_csr(const int* __restrict__ row_start,
                                                const long long* __restrict__ sedge,
                                                const float* __restrict__ x,
                                                float* __restrict__ y,
                                                float* __restrict__ out) {
    int w = blockIdx.x * 4 + (threadIdx.x >> 6);
    if (w >= N_NODES_) return;
    int lane = threadIdx.x & 63;
    int g = lane >> 4;
    int d = lane & 15;
    int s = row_start[w];
    int e = row_start[w + 1];
    float4 acc0 = make_float4(0.f, 0.f, 0.f, 0.f);
    float4 acc1 = make_float4(0.f, 0.f, 0.f, 0.f);
    for (int base = s; base < e; base += 64) {
        int n = e - base; if (n > 64) n = 64;
        int ec = 0; float ev = 0.f;
        if (lane < n) {
            long long p = __builtin_nontemporal_load(&sedge[base + lane]);
            ec = (int)(p & 0xffffffffLL);
            ev = __int_as_float((int)(p >> 32));
        }
        int nIter = (n + 3) >> 2;
        int j = 0;
        for (; j + 1 < nIter; j += 2) {
            int idx0 = (j << 2) + g;
            int idx1 = idx0 + 4;
            int   c0 = __shfl(ec, idx0);
            float v0 = __shfl(ev, idx0);
            int   c1 = __shfl(ec, idx1);
            float v1 = __shfl(ev, idx1);
            float4 xa = ((const float4*)(x + (size_t)c0 * DIM))[d];
            float4 xb = ((const float4*)(x + (size_t)c1 * DIM))[d];
            acc0.x += v0 * xa.x; acc0.y += v0 * xa.y; acc0.z += v0 * xa.z; acc0.w += v0 * xa.w;
            acc1.x += v1 * xb.x; acc1.y += v1 * xb.y; acc1.z += v1 * xb.z; acc1.w += v1 * xb.w;
        }
        if (j < nIter) {
            int idx0 = (j << 2) + g;
            int   c0 = __shfl(ec, idx0);
            float v0 = __shfl(ev, idx0);
            float4 xa = ((const float4*)(x + (size_t)c0 * DIM))[d];
            acc0.x += v0 * xa.x; acc0.y += v0 * xa.y; acc0.z += v0 * xa.z; acc0.w += v0 * xa.w;
        }
    }
    float4 acc;
    acc.x = acc0.x + acc1.x; acc.y = acc0.y + acc1.y;
    acc.z = acc0.z + acc1.z; acc.w = acc0.w + acc1.w;
    // reduce across the 4 edge-groups (lane bits 4 and 5)
    acc.x += __shfl_xor(acc.x, 16); acc.y += __shfl_xor(acc.y, 16);
    acc.z += __shfl_xor(acc.z, 16); acc.w += __shfl_xor(acc.w, 16);
    acc.x += __shfl_xor(acc.x, 32); acc.y += __shfl_xor(acc.y, 32);
    acc.z += __shfl_xor(acc.z, 32); acc.w += __shfl_xor(acc.w, 32);
    if (lane < 16) {
        size_t o = (size_t)w * 16 + d;           // float4 index
        float4* op = (float4*)out;
        float4 ov = op[o];
        if (FINAL) {
            ov.x = (ov.x + acc.x) * 0.25f;
            ov.y = (ov.y + acc.y) * 0.25f;
            ov.z = (ov.z + acc.z) * 0.25f;
            ov.w = (ov.w + acc.w) * 0.25f;
            op[o] = ov;
        } else {
            ((float4*)y)[o] = acc;
            ov.x += acc.x; ov.y += acc.y; ov.z += acc.z; ov.w += acc.w;
            op[o] = ov;
        }
    }
}

extern "C" void kernel_launch(void* const* d_in, const int* in_sizes, int n_in,
                              void* d_out, int out_size, void* d_ws, size_t ws_size,
                              hipStream_t stream) {
    const float* user_emb = (const float*)d_in[0];
    const float* item_emb = (const float*)d_in[1];
    const int*   rows     = (const int*)d_in[2];
    const int*   cols     = (const int*)d_in[3];
    const float* vals     = (const float*)d_in[4];
    float* out = (float*)d_out;

    const size_t nE = (size_t)N_NODES_ * DIM;          // 19.2M floats
    float* A         = (float*)d_ws;                   // 76.8 MB
    float* B         = A + nE;                         // 76.8 MB
    int*   row_start = (int*)(B + nE);                 // 300002 ints
    int*   cursor    = row_start + (N_NODES_ + 2);     // 300000 ints (aliases counts)
    int*   blockSums = cursor + N_NODES_;              // 256 ints
    long long* sedge = (long long*)(blockSums + 256);  // 32 MB, 8B-aligned

    int* counts = cursor;

    const int n_t4 = (int)(nE / 4);
    const int ew_grid = (n_t4 + 255) / 256;
    const int edge_grid = (NNZ_ + 255) / 256;
    const int spmm_grid = (N_NODES_ + 3) / 4;

    // ---- build CSR ----
    hipMemsetAsync(counts, 0, N_NODES_ * sizeof(int), stream);
    hist_kernel<<<edge_grid, 256, 0, stream>>>(rows, counts);
    scan_a<<<NBLK, 256, 0, stream>>>(counts, row_start, blockSums);
    scan_b<<<1, 256, 0, stream>>>(blockSums);
    scan_c<<<(N_NODES_ + 1 + 255) / 256, 256, 0, stream>>>(row_start, cursor, blockSums);
    scatter_kernel<<<edge_grid, 256, 0, stream>>>(rows, cols, vals, cursor, sedge);

    // ---- x0 = concat; out = x0 ----
    init_kernel<<<ew_grid, 256, 0, stream>>>((const float4*)user_emb,
                                             (const float4*)item_emb,
                                             (float4*)A, (float4*)out);
    // ---- layer 1: A -> B, out += x1 ----
    spmm_csr<0><<<spmm_grid, 256, 0, stream>>>(row_start, sedge, A, B, out);
    // ---- layer 2: B -> A, out += x2 ----
    spmm_csr<0><<<spmm_grid, 256, 0, stream>>>(row_start, sedge, B, A, out);
    // ---- layer 3: A -> (fused), out = (out + x3)/4 ----
    spmm_csr<1><<<spmm_grid, 256, 0, stream>>>(row_start, sedge, A, nullptr, out);
}

// Round 4
// 814.278 us; speedup vs baseline: 3.3666x; 1.4102x over previous
//
#include <hip/hip_runtime.h>

// LightGCN propagation: out = mean(x0..x3), x_{k+1} = SpMM(COO, x_k)
// v4: two-pass binned counting sort (L2-friendly writes) + bf16 intermediates.

#define N_USERS  100000
#define N_ITEMS  200000
#define N_NODES_ 300000
#define DIM      64
#define NNZ_     4000000
#define SCAN_CHUNK 2048
#define NBLK ((N_NODES_ + SCAN_CHUNK - 1) / SCAN_CHUNK)   // 147
#define BSHIFT   10
#define NBUCKET  ((N_NODES_ + 1023) >> 10)                // 293
#define PA_CHUNK 4096
#define PA_BLOCKS ((NNZ_ + PA_CHUNK - 1) / PA_CHUNK)      // 977

// ---- bf16 helpers (manual, RNE) ----
__device__ __forceinline__ unsigned short f2bf(float f) {
    unsigned u = __float_as_uint(f);
    unsigned r = 0x7fffu + ((u >> 16) & 1u);
    return (unsigned short)((u + r) >> 16);
}
__device__ __forceinline__ void fma8(float* acc, float v, uint4 r) {
    acc[0] = fmaf(v, __uint_as_float(r.x << 16), acc[0]);
    acc[1] = fmaf(v, __uint_as_float(r.x & 0xffff0000u), acc[1]);
    acc[2] = fmaf(v, __uint_as_float(r.y << 16), acc[2]);
    acc[3] = fmaf(v, __uint_as_float(r.y & 0xffff0000u), acc[3]);
    acc[4] = fmaf(v, __uint_as_float(r.z << 16), acc[4]);
    acc[5] = fmaf(v, __uint_as_float(r.z & 0xffff0000u), acc[5]);
    acc[6] = fmaf(v, __uint_as_float(r.w << 16), acc[6]);
    acc[7] = fmaf(v, __uint_as_float(r.w & 0xffff0000u), acc[7]);
}
__device__ __forceinline__ uint4 pack8(const float* f) {
    unsigned a = (unsigned)f2bf(f[0]) | ((unsigned)f2bf(f[1]) << 16);
    unsigned b = (unsigned)f2bf(f[2]) | ((unsigned)f2bf(f[3]) << 16);
    unsigned c = (unsigned)f2bf(f[4]) | ((unsigned)f2bf(f[5]) << 16);
    unsigned d = (unsigned)f2bf(f[6]) | ((unsigned)f2bf(f[7]) << 16);
    return make_uint4(a, b, c, d);
}
__device__ __forceinline__ void unpack8(float* f, uint4 r) {
    f[0] = __uint_as_float(r.x << 16); f[1] = __uint_as_float(r.x & 0xffff0000u);
    f[2] = __uint_as_float(r.y << 16); f[3] = __uint_as_float(r.y & 0xffff0000u);
    f[4] = __uint_as_float(r.z << 16); f[5] = __uint_as_float(r.z & 0xffff0000u);
    f[6] = __uint_as_float(r.w << 16); f[7] = __uint_as_float(r.w & 0xffff0000u);
}

// ---------------- init: Abf = bf16(concat(user,item)) ----------------
__global__ void init_bf(const float4* __restrict__ u, const float4* __restrict__ it,
                        uint4* __restrict__ Abf) {
    const int n_u = N_USERS * DIM / 8;   // 800000
    const int n_t = N_NODES_ * DIM / 8;  // 2400000
    int i = blockIdx.x * blockDim.x + threadIdx.x;
    if (i >= n_t) return;
    float4 a, b;
    if (i < n_u) { a = u[2 * i];           b = u[2 * i + 1]; }
    else         { int j = i - n_u; a = it[2 * j]; b = it[2 * j + 1]; }
    float f[8] = {a.x, a.y, a.z, a.w, b.x, b.y, b.z, b.w};
    Abf[i] = pack8(f);
}

// ---------------- histogram of row ids ----------------
__global__ void hist_kernel(const int* __restrict__ rows, int* __restrict__ counts) {
    int e = blockIdx.x * blockDim.x + threadIdx.x;
    if (e < NNZ_) atomicAdd(&counts[rows[e]], 1);
}

// ---------------- scan A/B/C ----------------
__global__ void scan_a(const int* __restrict__ counts, int* __restrict__ row_start,
                       int* __restrict__ blockSums) {
    __shared__ int lds[256];
    int tid = threadIdx.x;
    int base = blockIdx.x * SCAN_CHUNK + tid * 8;
    int v[8]; int sum = 0;
    #pragma unroll
    for (int k = 0; k < 8; ++k) {
        int idx = base + k;
        v[k] = (idx < N_NODES_) ? counts[idx] : 0;
        sum += v[k];
    }
    lds[tid] = sum;
    __syncthreads();
    for (int off = 1; off < 256; off <<= 1) {
        int t = (tid >= off) ? lds[tid - off] : 0;
        __syncthreads();
        lds[tid] += t;
        __syncthreads();
    }
    int excl = (tid == 0) ? 0 : lds[tid - 1];
    #pragma unroll
    for (int k = 0; k < 8; ++k) {
        int idx = base + k;
        if (idx < N_NODES_) row_start[idx] = excl;
        excl += v[k];
    }
    if (tid == 255) blockSums[blockIdx.x] = lds[255];
}

__global__ void scan_b(int* __restrict__ blockSums) {
    __shared__ int lds[256];
    int tid = threadIdx.x;
    int v = (tid < NBLK) ? blockSums[tid] : 0;
    lds[tid] = v;
    __syncthreads();
    for (int off = 1; off < 256; off <<= 1) {
        int t = (tid >= off) ? lds[tid - off] : 0;
        __syncthreads();
        lds[tid] += t;
        __syncthreads();
    }
    int excl = (tid == 0) ? 0 : lds[tid - 1];
    if (tid < NBLK) blockSums[tid] = excl;
}

__global__ void scan_c(int* __restrict__ row_start, const int* __restrict__ blockSums) {
    int idx = blockIdx.x * blockDim.x + threadIdx.x;
    if (idx < N_NODES_)       row_start[idx] += blockSums[idx >> 11];
    else if (idx == N_NODES_) row_start[idx] = NNZ_;
}

// ---------------- gcursor init (after row_start finalized) ----------------
__global__ void gcur_init(const int* __restrict__ row_start, int* __restrict__ gcursor) {
    int t = threadIdx.x;
    if (t < NBUCKET) gcursor[t] = row_start[t << BSHIFT];
}

// ---------------- pass A: block-local counting sort into row buckets ----------------
// entry: lo = col | (row_local10 << 19), hi = val bits
__global__ __launch_bounds__(256) void passA(const int* __restrict__ rows,
                                             const int* __restrict__ cols,
                                             const float* __restrict__ vals,
                                             int* __restrict__ gcursor,
                                             int2* __restrict__ binned) {
    __shared__ int hist[NBUCKET];
    __shared__ int gbase[NBUCKET];
    __shared__ int lcur[NBUCKET];
    int tid = threadIdx.x;
    int base = blockIdx.x * PA_CHUNK;
    int cnt = NNZ_ - base; if (cnt > PA_CHUNK) cnt = PA_CHUNK;
    for (int i = tid; i < NBUCKET; i += 256) hist[i] = 0;
    __syncthreads();
    for (int i = tid; i < cnt; i += 256) atomicAdd(&hist[rows[base + i] >> BSHIFT], 1);
    __syncthreads();
    for (int i = tid; i < NBUCKET; i += 256) {
        int c = hist[i];
        gbase[i] = c ? atomicAdd(&gcursor[i], c) : 0;
        lcur[i] = 0;
    }
    __syncthreads();
    for (int i = tid; i < cnt; i += 256) {
        int e = base + i;
        int r = rows[e];
        int b = r >> BSHIFT;
        int k = atomicAdd(&lcur[b], 1);
        int lo = cols[e] | ((r & 1023) << 19);
        binned[gbase[b] + k] = make_int2(lo, __float_as_int(vals[e]));
    }
}

// ---------------- pass B: within-bucket sort by row (L2-resident dest) ----------------
__global__ __launch_bounds__(1024) void passB(const int* __restrict__ row_start,
                                              const int2* __restrict__ binned,
                                              int2* __restrict__ sedge) {
    __shared__ int lcur[1024];
    int b = blockIdx.x;
    int rowbase = b << BSHIFT;
    int t = threadIdx.x;
    int gr = rowbase + t;
    lcur[t] = (gr < N_NODES_) ? row_start[gr] : 0;
    __syncthreads();
    int s = row_start[rowbase];
    int hi = rowbase + 1024; if (hi > N_NODES_) hi = N_NODES_;
    int e = row_start[hi];
    for (int i = s + t; i < e; i += 1024) {
        int2 p = binned[i];
        int rl = ((unsigned)p.x >> 19) & 1023;
        int pos = atomicAdd(&lcur[rl], 1);
        sedge[pos] = make_int2(p.x & 0x7ffff, p.y);
    }
}

// ---------------- CSR SpMM bf16: wave=row, 8 groups x 8 lanes x 16B ----------------
__global__ __launch_bounds__(256) void spmm_bf(const int* __restrict__ row_start,
                                               const int2* __restrict__ sedge,
                                               const uint4* __restrict__ x,
                                               uint4* __restrict__ y) {
    int w = blockIdx.x * 4 + (threadIdx.x >> 6);
    if (w >= N_NODES_) return;
    int lane = threadIdx.x & 63;
    int g = lane >> 3;
    int d = lane & 7;
    int s = row_start[w];
    int e = row_start[w + 1];
    float acc[8] = {0.f, 0.f, 0.f, 0.f, 0.f, 0.f, 0.f, 0.f};
    for (int base = s; base < e; base += 64) {
        int n = e - base; if (n > 64) n = 64;
        int ec = 0, ev = 0;
        if (lane < n) { int2 p = sedge[base + lane]; ec = p.x; ev = p.y; }
        int nG = (n + 7) >> 3;
        int j = 0;
        for (; j + 1 < nG; j += 2) {
            int i0 = (j << 3) + g;
            int i1 = i0 + 8;
            int   c0 = __shfl(ec, i0);
            float v0 = __int_as_float(__shfl(ev, i0));
            int   c1 = __shfl(ec, i1);
            float v1 = __int_as_float(__shfl(ev, i1));
            uint4 r0 = x[(size_t)c0 * 8 + d];
            uint4 r1 = x[(size_t)c1 * 8 + d];
            fma8(acc, v0, r0);
            fma8(acc, v1, r1);
        }
        if (j < nG) {
            int i0 = (j << 3) + g;
            int   c0 = __shfl(ec, i0);
            float v0 = __int_as_float(__shfl(ev, i0));
            uint4 r0 = x[(size_t)c0 * 8 + d];
            fma8(acc, v0, r0);
        }
    }
    #pragma unroll
    for (int k = 0; k < 8; ++k) {
        acc[k] += __shfl_xor(acc[k], 8);
        acc[k] += __shfl_xor(acc[k], 16);
        acc[k] += __shfl_xor(acc[k], 32);
    }
    if (lane < 8) y[(size_t)w * 8 + d] = pack8(acc);
}

// ---------------- final: out = (x0 + x1 + x2 + x3) * 0.25 ----------------
__global__ void final_mean(const float4* __restrict__ u, const float4* __restrict__ it,
                           const uint4* __restrict__ x1, const uint4* __restrict__ x2,
                           const uint4* __restrict__ x3, float4* __restrict__ out) {
    const int n_u = N_USERS * DIM / 8;
    const int n_t = N_NODES_ * DIM / 8;
    int i = blockIdx.x * blockDim.x + threadIdx.x;
    if (i >= n_t) return;
    float4 a, b;
    if (i < n_u) { a = u[2 * i];           b = u[2 * i + 1]; }
    else         { int j = i - n_u; a = it[2 * j]; b = it[2 * j + 1]; }
    float f0[8] = {a.x, a.y, a.z, a.w, b.x, b.y, b.z, b.w};
    float f1[8], f2[8], f3[8];
    unpack8(f1, x1[i]);
    unpack8(f2, x2[i]);
    unpack8(f3, x3[i]);
    float o[8];
    #pragma unroll
    for (int k = 0; k < 8; ++k) o[k] = (f0[k] + f1[k] + f2[k] + f3[k]) * 0.25f;
    out[2 * i]     = make_float4(o[0], o[1], o[2], o[3]);
    out[2 * i + 1] = make_float4(o[4], o[5], o[6], o[7]);
}

extern "C" void kernel_launch(void* const* d_in, const int* in_sizes, int n_in,
                              void* d_out, int out_size, void* d_ws, size_t ws_size,
                              hipStream_t stream) {
    const float* user_emb = (const float*)d_in[0];
    const float* item_emb = (const float*)d_in[1];
    const int*   rows     = (const int*)d_in[2];
    const int*   cols     = (const int*)d_in[3];
    const float* vals     = (const float*)d_in[4];
    float* out = (float*)d_out;

    const size_t nE = (size_t)N_NODES_ * DIM;   // 19.2M elems
    unsigned short* Abf = (unsigned short*)d_ws;            // 38.4 MB
    unsigned short* Bbf = Abf + nE;                         // 38.4 MB
    unsigned short* Cbf = Bbf + nE;                         // 38.4 MB
    int* row_start = (int*)(Cbf + nE);                      // N+2 ints
    int* counts    = row_start + (N_NODES_ + 2);            // N ints
    int* blockSums = counts + N_NODES_;                     // 256
    int* gcursor   = blockSums + 256;                       // 512 (pad to 8B)
    int2* binned   = (int2*)(gcursor + 512);                // 32 MB
    int2* sedge    = binned + NNZ_;                         // 32 MB

    const int n_t8 = (int)(nE / 8);                         // 2.4M
    const int ew_grid   = (n_t8 + 255) / 256;               // 9375
    const int edge_grid = (NNZ_ + 255) / 256;               // 15625
    const int spmm_grid = (N_NODES_ + 3) / 4;               // 75000

    // ---- build CSR via two-pass binned sort ----
    hipMemsetAsync(counts, 0, N_NODES_ * sizeof(int), stream);
    hist_kernel<<<edge_grid, 256, 0, stream>>>(rows, counts);
    scan_a<<<NBLK, 256, 0, stream>>>(counts, row_start, blockSums);
    scan_b<<<1, 256, 0, stream>>>(blockSums);
    scan_c<<<(N_NODES_ + 1 + 255) / 256, 256, 0, stream>>>(row_start, blockSums);
    gcur_init<<<1, 512, 0, stream>>>(row_start, gcursor);
    passA<<<PA_BLOCKS, 256, 0, stream>>>(rows, cols, vals, gcursor, binned);
    passB<<<NBUCKET, 1024, 0, stream>>>(row_start, binned, sedge);

    // ---- x0 (bf16) ----
    init_bf<<<ew_grid, 256, 0, stream>>>((const float4*)user_emb, (const float4*)item_emb,
                                         (uint4*)Abf);
    // ---- 3 layers: A->B->C->A ----
    spmm_bf<<<spmm_grid, 256, 0, stream>>>(row_start, sedge, (const uint4*)Abf, (uint4*)Bbf);
    spmm_bf<<<spmm_grid, 256, 0, stream>>>(row_start, sedge, (const uint4*)Bbf, (uint4*)Cbf);
    spmm_bf<<<spmm_grid, 256, 0, stream>>>(row_start, sedge, (const uint4*)Cbf, (uint4*)Abf);
    // ---- out = mean ----
    final_mean<<<ew_grid, 256, 0, stream>>>((const float4*)user_emb, (const float4*)item_emb,
                                            (const uint4*)Bbf, (const uint4*)Cbf,
                                            (const uint4*)Abf, (float4*)out);
}